// Round 10
// baseline (146.959 us; speedup 1.0000x reference)
//
#include <hip/hip_runtime.h>
#include <math.h>

#define HW2   62
#define NANCH 34596   // 62*62*9
#define NBAT  16
#define NGT   8
#define FEATC 256
#define NOUT  45      // 9 cls + 36 box channels
#define NBLK_E 2176   // epilogue blocks = 136*16

typedef short bf16x8 __attribute__((ext_vector_type(8)));
typedef float f32x4  __attribute__((ext_vector_type(4)));

#define AS1U(p) ((const __attribute__((address_space(1))) unsigned int*)(p))
#define AS3U(p) ((__attribute__((address_space(3))) unsigned int*)(p))

// fp32 -> bf16 round-to-nearest-even
__device__ __forceinline__ unsigned short f2bf(float f) {
    unsigned int u = __float_as_uint(f);
    u = u + 0x7FFFu + ((u >> 16) & 1u);
    return (unsigned short)(u >> 16);
}

// ---------- shared device helpers (bitwise identical to passing R2-R9) ----------

__device__ __forceinline__ void anchor4(int i, int j, int a,
                                        float& x1, float& y1, float& x2, float& y2) {
    int am = a % 3, ad = a / 3;
    float h = 2.f * (float)(am + 1);              // 2,4,6
    float w = h * 0.5f * (float)(1 << ad);        // h*{0.5,1,2}
    float cx = (float)i + 0.5f, cy = (float)j + 0.5f;
    x1 = fminf(fmaxf(cx - 0.5f * w, 0.f), 62.f);
    x2 = fminf(fmaxf(cx + 0.5f * w, 0.f), 62.f);
    y1 = fminf(fmaxf(cy - 0.5f * h, 0.f), 62.f);
    y2 = fminf(fmaxf(cy + 0.5f * h, 0.f), 62.f);
}

__device__ __forceinline__ float iou_fn(float ax1, float ay1, float ax2, float ay2,
                                        float gx1, float gy1, float gx2, float gy2) {
    float area_a = __fmul_rn(__fsub_rn(ax2, ax1), __fsub_rn(ay2, ay1));
    float area_g = __fmul_rn(__fsub_rn(gx2, gx1), __fsub_rn(gy2, gy1));
    float ix1 = fmaxf(ax1, gx1), iy1 = fmaxf(ay1, gy1);
    float ix2 = fminf(ax2, gx2), iy2 = fminf(ay2, gy2);
    float iw = fmaxf(__fsub_rn(ix2, ix1), 0.f);
    float ih = fmaxf(__fsub_rn(iy2, iy1), 0.f);
    float inter = __fmul_rn(iw, ih);
    float uni = __fsub_rn(__fadd_rn(area_a, area_g), inter);
    return inter / fmaxf(uni, 1e-9f);
}

__device__ __forceinline__ float softplus_f(float x) {
    return fmaxf(x, 0.f) + log1pf(expf(-fabsf(x)));
}

__device__ __forceinline__ float sl1_f(float d) {
    float ad = fabsf(d);
    return (ad < 1.f) ? 0.5f * d * d : (ad - 0.5f);
}

// ---------- to_bf16 body: fp32 NCHW -> bf16 [b][cc][cg][y][x][8ch] ----------
__device__ __forceinline__ void to_bf16_body(const float* __restrict__ feat,
                                             unsigned short* __restrict__ ft,
                                             float* ldsT,
                                             int yp, int cc, int bz, int b, int t) {
    int y0 = yp * 2;
#pragma unroll
    for (int k = 0; k < 4; ++k) {
        int fi = k * 256 + t;
        int ch = fi >> 5, r = fi & 31;
        int y = r >> 4, xq = r & 15;
        f32x4 v = *(const f32x4*)(feat + ((size_t)(b * 256 + cc * 32 + ch) << 12)
                                  + (y0 + y) * 64 + xq * 4);
        int word = ch * 128 + y * 64 + ((xq * 4) ^ ((ch & 7) << 3));
        *(f32x4*)(ldsT + word) = v;
    }
    __syncthreads();
    int y = t >> 7, x = (t >> 1) & 63, h2 = t & 1;
    bf16x8 o0, o1;
#pragma unroll
    for (int j = 0; j < 8; ++j) {
        int ch = h2 * 16 + j;
        o0[j] = (short)f2bf(ldsT[ch * 128 + y * 64 + (x ^ ((ch & 7) << 3))]);
    }
#pragma unroll
    for (int j = 0; j < 8; ++j) {
        int ch = h2 * 16 + 8 + j;
        o1[j] = (short)f2bf(ldsT[ch * 128 + y * 64 + (x ^ ((ch & 7) << 3))]);
    }
    unsigned short* ftc = ft + ((size_t)(bz * 8 + cc) << 17);
    size_t p = (size_t)(y0 + y) * 64 + x;
    *(bf16x8*)(ftc + ((size_t)(h2 * 2) * 4096 + p) * 8) = o0;
    *(bf16x8*)(ftc + ((size_t)(h2 * 2 + 1) * 4096 + p) * 8) = o1;
}

// ---------- Kernel 1: prep_all (fold | gt max-iou | effb+counter | to_bf16) ----------
__global__ void prep_all(const float* __restrict__ feat,
                         const float* __restrict__ conv_w,
                         const float* __restrict__ conv_b,
                         const float* __restrict__ cls_w,
                         const float* __restrict__ cls_b,
                         const float* __restrict__ box_w,
                         const float* __restrict__ box_b,
                         const float* __restrict__ gtb,
                         unsigned short* __restrict__ Bfrag,
                         float* __restrict__ effb,
                         float* __restrict__ maxiou,
                         unsigned int* __restrict__ counter,
                         unsigned short* __restrict__ ft) {
    __shared__ float ldsT[4096];
    __shared__ float red[256];
    int blk = blockIdx.x, t = threadIdx.x;
    if (blk < 432) {
        int i = blk * 256 + t;               // < 110592 = 48*2304
        int o = i / 2304, idx = i - o * 2304;
        float s = 0.f;
        if (o < NOUT) {
            const float* w2 = (o < 9) ? (cls_w + o * FEATC) : (box_w + (o - 9) * FEATC);
#pragma unroll 8
            for (int m = 0; m < FEATC; ++m)
                s = fmaf(w2[m], conv_w[(size_t)m * 2304 + idx], s);  // w2 uniform, conv_w coalesced
        }
        int c = idx / 9, tap = idx - c * 9;
        size_t slot = (((size_t)(c >> 5) * 9 + tap) * 3 + (o >> 4)) * 512
                    + (size_t)((((c >> 3) & 3) * 16) + (o & 15)) * 8 + (c & 7);
        Bfrag[slot] = f2bf(s);
    } else if (blk < 560) {
        int bg = blk - 432;
        int b = bg >> 3, g = bg & 7;
        const float* p = gtb + (b * NGT + g) * 4;
        float gx1 = p[0] * 0.125f, gy1 = p[1] * 0.125f;
        float gx2 = p[2] * 0.125f, gy2 = p[3] * 0.125f;
        float m = 0.f;
        for (int n = t; n < NANCH; n += 256) {
            int i = n / 558; int r = n - i * 558; int j = r / 9; int a = r - j * 9;
            float ax1, ay1, ax2, ay2;
            anchor4(i, j, a, ax1, ay1, ax2, ay2);
            m = fmaxf(m, iou_fn(ax1, ay1, ax2, ay2, gx1, gy1, gx2, gy2));
        }
        red[t] = m;
        __syncthreads();
        for (int s = 128; s > 0; s >>= 1) {
            if (t < s) red[t] = fmaxf(red[t], red[t + s]);
            __syncthreads();
        }
        if (t == 0) maxiou[bg] = red[0];
    } else if (blk == 560) {
        if (t == 0) *counter = 0u;
        if (t < 48) {
            float bv = 0.f;
            if (t < NOUT) {
                bv = (t < 9) ? cls_b[t] : box_b[t - 9];
                const float* w2 = (t < 9) ? (cls_w + t * FEATC) : (box_w + (t - 9) * FEATC);
                for (int mid = 0; mid < FEATC; ++mid) bv = fmaf(w2[mid], conv_b[mid], bv);
            }
            effb[t] = bv;
        }
    } else {
        int u = blk - 561;
        int yp = u & 31, cc = (u >> 5) & 7, bz = u >> 8;
        to_bf16_body(feat, ft, ldsT, yp, cc, bz, bz, t);
    }
}

// ---------- standalone to_bf16 for fallback batch groups ----------
__global__ void to_bf16(const float* __restrict__ feat,
                        unsigned short* __restrict__ ft, int b_base) {
    __shared__ float ldsT[4096];
    to_bf16_body(feat, ft, ldsT, blockIdx.x, blockIdx.y, blockIdx.z,
                 b_base + blockIdx.z, threadIdx.x);
}

// ---------- Kernel 2: PURE MFMA conv -> convOut[b][pix3844][48] ----------
// grid 31*g (XCD-swizzled), 256 threads (4 waves). Band = 2 rows (124 pixels).
// Wave w: pixels w*32..w*32+31 (2 m-frags x 3 n-frags); 8 K-chunks, B LDS-dbuf,
// A direct-global; 1 barrier/chunk. No epilogue baggage (ablation split R10).
__launch_bounds__(256, 2)
__global__ void conv_mfma(const unsigned short* __restrict__ ft,
                          const unsigned short* __restrict__ Bfrag,
                          const float* __restrict__ effb,
                          float* __restrict__ convOut,
                          int b_base) {
    __shared__ __align__(16) unsigned char smem[55296];  // B dbuf 2 x 27648

    const int t = threadIdx.x, l = t & 63, w = t >> 6;
    const int l15 = l & 15, lq = l >> 4;

    // bijective XCD swizzle (m204 general form)
    int nwg = gridDim.x;
    int q = nwg >> 3, r = nwg & 7;
    int xcd = blockIdx.x & 7, within = blockIdx.x >> 3;
    int wgid = ((xcd < r) ? xcd * (q + 1) : r * (q + 1) + (xcd - r) * q) + within;
    const int band = wgid % 31, bz = wgid / 31;
    const int b = b_base + bz;
    const int y0 = band * 2;

    f32x4 acc[2][3];
#pragma unroll
    for (int nf = 0; nf < 3; ++nf) {
        float bv = effb[nf * 16 + l15];
#pragma unroll
        for (int mf = 0; mf < 2; ++mf)
#pragma unroll
            for (int r2 = 0; r2 < 4; ++r2) acc[mf][nf][r2] = bv;
    }

    int p0 = w * 32 + l15;      if (p0 > 123) p0 = 123;
    int p1 = w * 32 + 16 + l15; if (p1 > 123) p1 = 123;
    int rr0 = p0 / 62, c0 = p0 - rr0 * 62;
    int rr1 = p1 / 62, c1 = p1 - rr1 * 62;
    const int aoff0 = (lq << 12) + (y0 + rr0) * 64 + c0;   // 16B units; y0+rr+dy<=63 safe
    const int aoff1 = (lq << 12) + (y0 + rr1) * 64 + c1;

    auto loadB = [&](int cc, int buf) {
        const unsigned short* Bt = Bfrag + (size_t)cc * 13824;
#pragma unroll
        for (int k = 0; k < 7; ++k) {                 // 1728 units of 16B
            int u = t + k * 256;
            if (u < 1728)
                __builtin_amdgcn_global_load_lds(AS1U(Bt + (size_t)u * 8),
                                                 AS3U(smem + buf * 27648 + u * 16), 16, 0, 0);
        }
    };
    auto computeChunk = [&](int cc, int buf) {
        const unsigned short* ftc = ft + ((size_t)(bz * 8 + cc) << 17);
        bf16x8 A0[9], A1[9];
#pragma unroll
        for (int tap = 0; tap < 9; ++tap) {
            int d = (tap / 3) * 64 + (tap % 3);
            A0[tap] = *(const bf16x8*)(ftc + (size_t)(aoff0 + d) * 8);
            A1[tap] = *(const bf16x8*)(ftc + (size_t)(aoff1 + d) * 8);
        }
        const char* Bb = (const char*)smem + buf * 27648;
#pragma unroll
        for (int tap = 0; tap < 9; ++tap) {
#pragma unroll
            for (int nf = 0; nf < 3; ++nf) {
                bf16x8 bfr = *(const bf16x8*)(Bb + (((tap * 3 + nf) << 6) + l) * 16);
                acc[0][nf] = __builtin_amdgcn_mfma_f32_16x16x32_bf16(A0[tap], bfr, acc[0][nf], 0, 0, 0);
                acc[1][nf] = __builtin_amdgcn_mfma_f32_16x16x32_bf16(A1[tap], bfr, acc[1][nf], 0, 0, 0);
            }
        }
    };

    loadB(0, 0);
    __syncthreads();
    for (int cc = 0; cc < 8; ++cc) {
        if (cc < 7) loadB(cc + 1, (cc + 1) & 1);
        computeChunk(cc, cc & 1);
        __syncthreads();
    }

    // store C -> convOut[(b*3844 + band*124 + pix)*48 + ch]
    float* co = convOut + ((size_t)b * 3844 + (size_t)band * 124) * 48;
#pragma unroll
    for (int mf = 0; mf < 2; ++mf)
#pragma unroll
        for (int nf = 0; nf < 3; ++nf)
#pragma unroll
            for (int r2 = 0; r2 < 4; ++r2) {
                int pix = w * 32 + mf * 16 + lq * 4 + r2;
                if (pix < 124) co[(size_t)pix * 48 + nf * 16 + l15] = acc[mf][nf][r2];
            }
}

// ---------- Kernel 3: epilogue (per-anchor, high occupancy) + fused finalize ----------
// grid (136, 16), 256 threads; thread <-> one anchor. nblk = 2176.
__global__ void epilogue_k(const float* __restrict__ convOut,
                           const float* __restrict__ gtb,
                           const int* __restrict__ gtc,
                           const float* __restrict__ maxiou,
                           float* __restrict__ outp,
                           float* __restrict__ blksums,
                           unsigned int* __restrict__ counter) {
    __shared__ float gshr[40];
    __shared__ float redl[256];
    __shared__ float tot[5];
    __shared__ unsigned int lastflag;

    const int t = threadIdx.x, b = blockIdx.y;
    if (t < 32) gshr[t] = gtb[b * 32 + t] * 0.125f;
    else if (t < 40) gshr[t] = maxiou[b * 8 + (t - 32)];
    __syncthreads();

    float s_pos = 0.f, s_neg = 0.f, s_pl = 0.f, s_nl = 0.f, s_reg = 0.f;
    float* out_prop = outp + 2;
    float* out_mask = out_prop + (size_t)NBAT * NANCH * 4;
    float* out_gtc  = out_mask + (size_t)NBAT * NANCH * 8;

    int an = blockIdx.x * 256 + t;
    if (an < NANCH) {
        int pix = an / 9, a = an - pix * 9;
        int oy = pix / 62, ox = pix - oy * 62;
        const float* cp = convOut + ((size_t)b * 3844 + pix) * 48;
        float cls = cp[a];
        float p0f = cp[9 + 4 * a];
        float p1f = cp[10 + 4 * a];
        float p2f = cp[11 + 4 * a];
        float p3f = cp[12 + 4 * a];

        float ax1, ay1, ax2, ay2;
        anchor4(oy, ox, a, ax1, ay1, ax2, ay2);
        float aw = ax2 - ax1, ah = ay2 - ay1;
        float acx = 0.5f * (ax1 + ax2), acy = 0.5f * (ay1 + ay2);

        const float ps = 64.f / 62.f;
        float pcx = acx + p0f * aw, pcy = acy + p1f * ah;
        float pw = aw * expf(p2f), ph = ah * expf(p3f);
        f32x4 prop = { (pcx - 0.5f * pw) * ps, (pcy - 0.5f * ph) * ps,
                       (pcx + 0.5f * pw) * ps, (pcy + 0.5f * ph) * ps };
        *(f32x4*)(out_prop + ((size_t)b * NANCH + an) * 4) = prop;   // an == n

        float law = logf(aw), lah = logf(ah);
        float posf_tot = 0.f, negf_tot = 0.f;
        float best_iou = -1.f; int best_g = 0;
        float pfv[8];
#pragma unroll
        for (int g = 0; g < NGT; ++g) {
            float gx1 = gshr[g * 4 + 0], gy1 = gshr[g * 4 + 1];
            float gx2 = gshr[g * 4 + 2], gy2 = gshr[g * 4 + 3];
            float iou = iou_fn(ax1, ay1, ax2, ay2, gx1, gy1, gx2, gy2);
            float mpg = gshr[32 + g];
            bool pm = ((iou == mpg) && (mpg > 0.f)) || (iou > 0.7f);
            float pf = pm ? 1.f : 0.f;
            float nf = (iou < 0.3f) ? 1.f : 0.f;
            pfv[g] = pf;
            posf_tot += pf; negf_tot += nf;
            if (iou > best_iou) { best_iou = iou; best_g = g; }  // first-max-wins
            if (pm) {
                float gw = gx2 - gx1, gh = gy2 - gy1;
                float gcx = 0.5f * (gx1 + gx2), gcy = 0.5f * (gy1 + gy2);
                float tx_ = (gcx - acx) / aw, ty_ = (gcy - acy) / ah;
                float tw_ = logf(gw) - law, th_ = logf(gh) - lah;
                float d0 = p0f - tx_, d1 = p1f - ty_, d2 = p2f - tw_, d3 = p3f - th_;
                s_reg += sl1_f(d0) + sl1_f(d1) + sl1_f(d2) + sl1_f(d3);
            }
        }
        size_t mb = ((size_t)b * NANCH + an) * 8;
        f32x4 m0 = { pfv[0], pfv[1], pfv[2], pfv[3] };
        f32x4 m1 = { pfv[4], pfv[5], pfv[6], pfv[7] };
        *(f32x4*)(out_mask + mb) = m0;
        *(f32x4*)(out_mask + mb + 4) = m1;
        s_pos = posf_tot; s_neg = negf_tot;
        s_pl = softplus_f(-cls) * posf_tot;
        s_nl = softplus_f(cls) * negf_tot;
        out_gtc[(size_t)b * NANCH + an] = (float)gtc[b * NGT + best_g];
    }

    // deterministic per-block tree reduction of the 5 loss partials
    int blk = b * 136 + blockIdx.x;
    float vals[5] = {s_pos, s_neg, s_pl, s_nl, s_reg};
#pragma unroll
    for (int s = 0; s < 5; ++s) {
        redl[t] = vals[s];
        __syncthreads();
        for (int st = 128; st > 0; st >>= 1) {
            if (t < st) redl[t] += redl[t + st];
            __syncthreads();
        }
        if (t == 0) blksums[(size_t)s * NBLK_E + blk] = redl[0];
        __syncthreads();
    }

    // fused finalize: last block (fence+atomic) does the fixed-order reduce
    if (t == 0) {
        __threadfence();
        lastflag = (atomicAdd(counter, 1u) == NBLK_E - 1u) ? 1u : 0u;
    }
    __syncthreads();
    if (lastflag) {
        __threadfence();
#pragma unroll
        for (int s = 0; s < 5; ++s) {
            float a = 0.f;
            for (int i = t; i < NBLK_E; i += 256) a += blksums[(size_t)s * NBLK_E + i];
            redl[t] = a;
            __syncthreads();
            for (int st = 128; st > 0; st >>= 1) {
                if (t < st) redl[t] += redl[t + st];
                __syncthreads();
            }
            if (t == 0) tot[s] = redl[0];
            __syncthreads();
        }
        if (t == 0) {
            float np_ = fmaxf(tot[0], 1.f), nn_ = fmaxf(tot[1], 1.f);
            outp[0] = 0.5f * (tot[2] / np_ + tot[3] / nn_);  // cls_loss
            outp[1] = tot[4] / (np_ * 4.f);                  // reg_loss
        }
    }
}

extern "C" void kernel_launch(void* const* d_in, const int* in_sizes, int n_in,
                              void* d_out, int out_size, void* d_ws, size_t ws_size,
                              hipStream_t stream) {
    (void)in_sizes; (void)n_in; (void)out_size;
    const float* feat   = (const float*)d_in[0];
    const float* gtb    = (const float*)d_in[1];
    const int*   gtc    = (const int*)d_in[2];
    const float* conv_w = (const float*)d_in[3];
    const float* conv_b = (const float*)d_in[4];
    const float* cls_w  = (const float*)d_in[5];
    const float* cls_b  = (const float*)d_in[6];
    const float* box_w  = (const float*)d_in[7];
    const float* box_b  = (const float*)d_in[8];
    float* outp = (float*)d_out;
    float* ws   = (float*)d_ws;

    // workspace layout (floats)
    unsigned short* Bfrag   = (unsigned short*)ws;            // 110592 us = 55296 fl
    float*          effb    = ws + 55296;                     // 64
    float*          maxiou  = ws + 55360;                     // 128
    unsigned int*   counter = (unsigned int*)(ws + 55488);    // 64
    float*          blksums = ws + 55552;                     // 5*2176 = 10880 -> pad 11264
    float*          convOut = ws + 66816;                     // 16*3844*48 = 2951168
    unsigned short* ft      = (unsigned short*)(ws + 3017984); // g * 1048576 ushorts

    // batch-group size: largest g in {16,8,4,2,1} that fits the workspace
    size_t avail = ws_size / 4;
    int g = 16;
    while (g > 1 && (size_t)3017984 + (size_t)g * 524288 > avail) g >>= 1;
    int g0 = g;

    prep_all<<<561 + 256 * g0, 256, 0, stream>>>(feat, conv_w, conv_b, cls_w, cls_b,
                                                 box_w, box_b, gtb, Bfrag, effb, maxiou,
                                                 counter, ft);
    conv_mfma<<<31 * g0, 256, 0, stream>>>(ft, Bfrag, effb, convOut, 0);
    for (int b0 = g0; b0 < NBAT; b0 += g) {
        to_bf16<<<dim3(32, 8, g), 256, 0, stream>>>(feat, ft, b0);
        conv_mfma<<<31 * g, 256, 0, stream>>>(ft, Bfrag, effb, convOut, b0);
    }
    epilogue_k<<<dim3(136, NBAT), 256, 0, stream>>>(convOut, gtb, gtc, maxiou,
                                                    outp, blksums, counter);
}

// Round 11
// 81.414 us; speedup vs baseline: 1.8051x; 1.8051x over previous
//
#include <hip/hip_runtime.h>
#include <math.h>

#define HW2   62
#define NANCH 34596   // 62*62*9
#define NBAT  16
#define NGT   8
#define FEATC 256
#define NOUT  45      // 9 cls + 36 box channels
#define NBLK_E 2176   // epilogue blocks = 136*16

typedef short bf16x8 __attribute__((ext_vector_type(8)));
typedef float f32x4  __attribute__((ext_vector_type(4)));
typedef float f32x2  __attribute__((ext_vector_type(2)));

#define AS1U(p) ((const __attribute__((address_space(1))) unsigned int*)(p))
#define AS3U(p) ((__attribute__((address_space(3))) unsigned int*)(p))

// fp32 -> bf16 round-to-nearest-even
__device__ __forceinline__ unsigned short f2bf(float f) {
    unsigned int u = __float_as_uint(f);
    u = u + 0x7FFFu + ((u >> 16) & 1u);
    return (unsigned short)(u >> 16);
}

// ---------- shared device helpers (bitwise identical to passing R2-R10) ----------

__device__ __forceinline__ void anchor4(int i, int j, int a,
                                        float& x1, float& y1, float& x2, float& y2) {
    int am = a % 3, ad = a / 3;
    float h = 2.f * (float)(am + 1);              // 2,4,6
    float w = h * 0.5f * (float)(1 << ad);        // h*{0.5,1,2}
    float cx = (float)i + 0.5f, cy = (float)j + 0.5f;
    x1 = fminf(fmaxf(cx - 0.5f * w, 0.f), 62.f);
    x2 = fminf(fmaxf(cx + 0.5f * w, 0.f), 62.f);
    y1 = fminf(fmaxf(cy - 0.5f * h, 0.f), 62.f);
    y2 = fminf(fmaxf(cy + 0.5f * h, 0.f), 62.f);
}

__device__ __forceinline__ float iou_fn(float ax1, float ay1, float ax2, float ay2,
                                        float gx1, float gy1, float gx2, float gy2) {
    float area_a = __fmul_rn(__fsub_rn(ax2, ax1), __fsub_rn(ay2, ay1));
    float area_g = __fmul_rn(__fsub_rn(gx2, gx1), __fsub_rn(gy2, gy1));
    float ix1 = fmaxf(ax1, gx1), iy1 = fmaxf(ay1, gy1);
    float ix2 = fminf(ax2, gx2), iy2 = fminf(ay2, gy2);
    float iw = fmaxf(__fsub_rn(ix2, ix1), 0.f);
    float ih = fmaxf(__fsub_rn(iy2, iy1), 0.f);
    float inter = __fmul_rn(iw, ih);
    float uni = __fsub_rn(__fadd_rn(area_a, area_g), inter);
    return inter / fmaxf(uni, 1e-9f);
}

__device__ __forceinline__ float softplus_f(float x) {
    return fmaxf(x, 0.f) + log1pf(expf(-fabsf(x)));
}

__device__ __forceinline__ float sl1_f(float d) {
    float ad = fabsf(d);
    return (ad < 1.f) ? 0.5f * d * d : (ad - 0.5f);
}

// ---------- to_bf16 body: fp32 NCHW -> bf16 [b][cc][cg][y][x][8ch] ----------
__device__ __forceinline__ void to_bf16_body(const float* __restrict__ feat,
                                             unsigned short* __restrict__ ft,
                                             float* ldsT,
                                             int yp, int cc, int bz, int b, int t) {
    int y0 = yp * 2;
#pragma unroll
    for (int k = 0; k < 4; ++k) {
        int fi = k * 256 + t;
        int ch = fi >> 5, r = fi & 31;
        int y = r >> 4, xq = r & 15;
        f32x4 v = *(const f32x4*)(feat + ((size_t)(b * 256 + cc * 32 + ch) << 12)
                                  + (y0 + y) * 64 + xq * 4);
        int word = ch * 128 + y * 64 + ((xq * 4) ^ ((ch & 7) << 3));
        *(f32x4*)(ldsT + word) = v;
    }
    __syncthreads();
    int y = t >> 7, x = (t >> 1) & 63, h2 = t & 1;
    bf16x8 o0, o1;
#pragma unroll
    for (int j = 0; j < 8; ++j) {
        int ch = h2 * 16 + j;
        o0[j] = (short)f2bf(ldsT[ch * 128 + y * 64 + (x ^ ((ch & 7) << 3))]);
    }
#pragma unroll
    for (int j = 0; j < 8; ++j) {
        int ch = h2 * 16 + 8 + j;
        o1[j] = (short)f2bf(ldsT[ch * 128 + y * 64 + (x ^ ((ch & 7) << 3))]);
    }
    unsigned short* ftc = ft + ((size_t)(bz * 8 + cc) << 17);
    size_t p = (size_t)(y0 + y) * 64 + x;
    *(bf16x8*)(ftc + ((size_t)(h2 * 2) * 4096 + p) * 8) = o0;
    *(bf16x8*)(ftc + ((size_t)(h2 * 2 + 1) * 4096 + p) * 8) = o1;
}

// ---------- Kernel 1: prep_all (fold | gt max-iou | effb | to_bf16) ----------
__global__ void prep_all(const float* __restrict__ feat,
                         const float* __restrict__ conv_w,
                         const float* __restrict__ conv_b,
                         const float* __restrict__ cls_w,
                         const float* __restrict__ cls_b,
                         const float* __restrict__ box_w,
                         const float* __restrict__ box_b,
                         const float* __restrict__ gtb,
                         unsigned short* __restrict__ Bfrag,
                         float* __restrict__ effb,
                         float* __restrict__ maxiou,
                         unsigned short* __restrict__ ft) {
    __shared__ float ldsT[4096];
    __shared__ float red[256];
    int blk = blockIdx.x, t = threadIdx.x;
    if (blk < 432) {
        int i = blk * 256 + t;               // < 110592 = 48*2304
        int o = i / 2304, idx = i - o * 2304;
        float s = 0.f;
        if (o < NOUT) {
            const float* w2 = (o < 9) ? (cls_w + o * FEATC) : (box_w + (o - 9) * FEATC);
#pragma unroll 8
            for (int m = 0; m < FEATC; ++m)
                s = fmaf(w2[m], conv_w[(size_t)m * 2304 + idx], s);  // w2 uniform, conv_w coalesced
        }
        int c = idx / 9, tap = idx - c * 9;
        size_t slot = (((size_t)(c >> 5) * 9 + tap) * 3 + (o >> 4)) * 512
                    + (size_t)((((c >> 3) & 3) * 16) + (o & 15)) * 8 + (c & 7);
        Bfrag[slot] = f2bf(s);
    } else if (blk < 560) {
        int bg = blk - 432;
        int b = bg >> 3, g = bg & 7;
        const float* p = gtb + (b * NGT + g) * 4;
        float gx1 = p[0] * 0.125f, gy1 = p[1] * 0.125f;
        float gx2 = p[2] * 0.125f, gy2 = p[3] * 0.125f;
        float m = 0.f;
        for (int n = t; n < NANCH; n += 256) {
            int i = n / 558; int r = n - i * 558; int j = r / 9; int a = r - j * 9;
            float ax1, ay1, ax2, ay2;
            anchor4(i, j, a, ax1, ay1, ax2, ay2);
            m = fmaxf(m, iou_fn(ax1, ay1, ax2, ay2, gx1, gy1, gx2, gy2));
        }
        red[t] = m;
        __syncthreads();
        for (int s = 128; s > 0; s >>= 1) {
            if (t < s) red[t] = fmaxf(red[t], red[t + s]);
            __syncthreads();
        }
        if (t == 0) maxiou[bg] = red[0];
    } else if (blk == 560) {
        if (t < 48) {
            float bv = 0.f;
            if (t < NOUT) {
                bv = (t < 9) ? cls_b[t] : box_b[t - 9];
                const float* w2 = (t < 9) ? (cls_w + t * FEATC) : (box_w + (t - 9) * FEATC);
                for (int mid = 0; mid < FEATC; ++mid) bv = fmaf(w2[mid], conv_b[mid], bv);
            }
            effb[t] = bv;
        }
    } else {
        int u = blk - 561;
        int yp = u & 31, cc = (u >> 5) & 7, bz = u >> 8;
        to_bf16_body(feat, ft, ldsT, yp, cc, bz, bz, t);
    }
}

// ---------- standalone to_bf16 for fallback batch groups ----------
__global__ void to_bf16(const float* __restrict__ feat,
                        unsigned short* __restrict__ ft, int b_base) {
    __shared__ float ldsT[4096];
    to_bf16_body(feat, ft, ldsT, blockIdx.x, blockIdx.y, blockIdx.z,
                 b_base + blockIdx.z, threadIdx.x);
}

// ---------- Kernel 2: PURE MFMA conv -> convOut[b][pix3844][48] ----------
__launch_bounds__(256, 2)
__global__ void conv_mfma(const unsigned short* __restrict__ ft,
                          const unsigned short* __restrict__ Bfrag,
                          const float* __restrict__ effb,
                          float* __restrict__ convOut,
                          int b_base) {
    __shared__ __align__(16) unsigned char smem[55296];  // B dbuf 2 x 27648

    const int t = threadIdx.x, l = t & 63, w = t >> 6;
    const int l15 = l & 15, lq = l >> 4;

    // bijective XCD swizzle (m204 general form)
    int nwg = gridDim.x;
    int q = nwg >> 3, r = nwg & 7;
    int xcd = blockIdx.x & 7, within = blockIdx.x >> 3;
    int wgid = ((xcd < r) ? xcd * (q + 1) : r * (q + 1) + (xcd - r) * q) + within;
    const int band = wgid % 31, bz = wgid / 31;
    const int b = b_base + bz;
    const int y0 = band * 2;

    f32x4 acc[2][3];
#pragma unroll
    for (int nf = 0; nf < 3; ++nf) {
        float bv = effb[nf * 16 + l15];
#pragma unroll
        for (int mf = 0; mf < 2; ++mf)
#pragma unroll
            for (int r2 = 0; r2 < 4; ++r2) acc[mf][nf][r2] = bv;
    }

    int p0 = w * 32 + l15;      if (p0 > 123) p0 = 123;
    int p1 = w * 32 + 16 + l15; if (p1 > 123) p1 = 123;
    int rr0 = p0 / 62, c0 = p0 - rr0 * 62;
    int rr1 = p1 / 62, c1 = p1 - rr1 * 62;
    const int aoff0 = (lq << 12) + (y0 + rr0) * 64 + c0;   // 16B units; y0+rr+dy<=63 safe
    const int aoff1 = (lq << 12) + (y0 + rr1) * 64 + c1;

    auto loadB = [&](int cc, int buf) {
        const unsigned short* Bt = Bfrag + (size_t)cc * 13824;
#pragma unroll
        for (int k = 0; k < 7; ++k) {                 // 1728 units of 16B
            int u = t + k * 256;
            if (u < 1728)
                __builtin_amdgcn_global_load_lds(AS1U(Bt + (size_t)u * 8),
                                                 AS3U(smem + buf * 27648 + u * 16), 16, 0, 0);
        }
    };
    auto computeChunk = [&](int cc, int buf) {
        const unsigned short* ftc = ft + ((size_t)(bz * 8 + cc) << 17);
        bf16x8 A0[9], A1[9];
#pragma unroll
        for (int tap = 0; tap < 9; ++tap) {
            int d = (tap / 3) * 64 + (tap % 3);
            A0[tap] = *(const bf16x8*)(ftc + (size_t)(aoff0 + d) * 8);
            A1[tap] = *(const bf16x8*)(ftc + (size_t)(aoff1 + d) * 8);
        }
        const char* Bb = (const char*)smem + buf * 27648;
#pragma unroll
        for (int tap = 0; tap < 9; ++tap) {
#pragma unroll
            for (int nf = 0; nf < 3; ++nf) {
                bf16x8 bfr = *(const bf16x8*)(Bb + (((tap * 3 + nf) << 6) + l) * 16);
                acc[0][nf] = __builtin_amdgcn_mfma_f32_16x16x32_bf16(A0[tap], bfr, acc[0][nf], 0, 0, 0);
                acc[1][nf] = __builtin_amdgcn_mfma_f32_16x16x32_bf16(A1[tap], bfr, acc[1][nf], 0, 0, 0);
            }
        }
    };

    loadB(0, 0);
    __syncthreads();
    for (int cc = 0; cc < 8; ++cc) {
        if (cc < 7) loadB(cc + 1, (cc + 1) & 1);
        computeChunk(cc, cc & 1);
        __syncthreads();
    }

    // store C -> convOut[(b*3844 + band*124 + pix)*48 + ch]
    float* co = convOut + ((size_t)b * 3844 + (size_t)band * 124) * 48;
#pragma unroll
    for (int mf = 0; mf < 2; ++mf)
#pragma unroll
        for (int nf = 0; nf < 3; ++nf)
#pragma unroll
            for (int r2 = 0; r2 < 4; ++r2) {
                int pix = w * 32 + mf * 16 + lq * 4 + r2;
                if (pix < 124) co[(size_t)pix * 48 + nf * 16 + l15] = acc[mf][nf][r2];
            }
}

// ---------- Kernel 3: epilogue (per-anchor, high occupancy, NO fences) ----------
// grid (136, 16), 256 threads; thread <-> one anchor. nblk = 2176.
__global__ void epilogue_k(const float* __restrict__ convOut,
                           const float* __restrict__ gtb,
                           const int* __restrict__ gtc,
                           const float* __restrict__ maxiou,
                           float* __restrict__ outp,
                           float* __restrict__ blksums) {
    __shared__ float gshr[40];
    __shared__ float redl[256];

    const int t = threadIdx.x, b = blockIdx.y;
    if (t < 32) gshr[t] = gtb[b * 32 + t] * 0.125f;
    else if (t < 40) gshr[t] = maxiou[b * 8 + (t - 32)];
    __syncthreads();

    float s_pos = 0.f, s_neg = 0.f, s_pl = 0.f, s_nl = 0.f, s_reg = 0.f;
    float* out_prop = outp + 2;
    float* out_mask = out_prop + (size_t)NBAT * NANCH * 4;
    float* out_gtc  = out_mask + (size_t)NBAT * NANCH * 8;

    int an = blockIdx.x * 256 + t;
    if (an < NANCH) {
        int pix = an / 9, a = an - pix * 9;
        int oy = pix / 62, ox = pix - oy * 62;
        const float* cp = convOut + ((size_t)b * 3844 + pix) * 48;
        float cls = cp[a];
        float p0f = cp[9 + 4 * a];
        float p1f = cp[10 + 4 * a];
        float p2f = cp[11 + 4 * a];
        float p3f = cp[12 + 4 * a];

        float ax1, ay1, ax2, ay2;
        anchor4(oy, ox, a, ax1, ay1, ax2, ay2);
        float aw = ax2 - ax1, ah = ay2 - ay1;
        float acx = 0.5f * (ax1 + ax2), acy = 0.5f * (ay1 + ay2);

        const float ps = 64.f / 62.f;
        float pcx = acx + p0f * aw, pcy = acy + p1f * ah;
        float pw = aw * expf(p2f), ph = ah * expf(p3f);
        // outputs start at float offset 2 -> 8B alignment; use float2 stores
        float* pp = out_prop + ((size_t)b * NANCH + an) * 4;
        f32x2 pr0 = { (pcx - 0.5f * pw) * ps, (pcy - 0.5f * ph) * ps };
        f32x2 pr1 = { (pcx + 0.5f * pw) * ps, (pcy + 0.5f * ph) * ps };
        *(f32x2*)(pp) = pr0;
        *(f32x2*)(pp + 2) = pr1;

        float law = logf(aw), lah = logf(ah);
        float posf_tot = 0.f, negf_tot = 0.f;
        float best_iou = -1.f; int best_g = 0;
        float pfv[8];
#pragma unroll
        for (int g = 0; g < NGT; ++g) {
            float gx1 = gshr[g * 4 + 0], gy1 = gshr[g * 4 + 1];
            float gx2 = gshr[g * 4 + 2], gy2 = gshr[g * 4 + 3];
            float iou = iou_fn(ax1, ay1, ax2, ay2, gx1, gy1, gx2, gy2);
            float mpg = gshr[32 + g];
            bool pm = ((iou == mpg) && (mpg > 0.f)) || (iou > 0.7f);
            float pf = pm ? 1.f : 0.f;
            float nf = (iou < 0.3f) ? 1.f : 0.f;
            pfv[g] = pf;
            posf_tot += pf; negf_tot += nf;
            if (iou > best_iou) { best_iou = iou; best_g = g; }  // first-max-wins
            if (pm) {
                float gw = gx2 - gx1, gh = gy2 - gy1;
                float gcx = 0.5f * (gx1 + gx2), gcy = 0.5f * (gy1 + gy2);
                float tx_ = (gcx - acx) / aw, ty_ = (gcy - acy) / ah;
                float tw_ = logf(gw) - law, th_ = logf(gh) - lah;
                float d0 = p0f - tx_, d1 = p1f - ty_, d2 = p2f - tw_, d3 = p3f - th_;
                s_reg += sl1_f(d0) + sl1_f(d1) + sl1_f(d2) + sl1_f(d3);
            }
        }
        float* mp = out_mask + ((size_t)b * NANCH + an) * 8;
#pragma unroll
        for (int g = 0; g < 8; g += 2) {
            f32x2 mv = { pfv[g], pfv[g + 1] };
            *(f32x2*)(mp + g) = mv;
        }
        s_pos = posf_tot; s_neg = negf_tot;
        s_pl = softplus_f(-cls) * posf_tot;
        s_nl = softplus_f(cls) * negf_tot;
        out_gtc[(size_t)b * NANCH + an] = (float)gtc[b * NGT + best_g];
    }

    // deterministic per-block tree reduction of the 5 loss partials
    int blk = b * 136 + blockIdx.x;
    float vals[5] = {s_pos, s_neg, s_pl, s_nl, s_reg};
#pragma unroll
    for (int s = 0; s < 5; ++s) {
        redl[t] = vals[s];
        __syncthreads();
        for (int st = 128; st > 0; st >>= 1) {
            if (t < st) redl[t] += redl[t + st];
            __syncthreads();
        }
        if (t == 0) blksums[(size_t)s * NBLK_E + blk] = redl[0];
        __syncthreads();
    }
}

// ---------- Kernel 4: finalize (1 block, fixed-order reduce; no device fences) ----------
__global__ void finalize(const float* __restrict__ blksums, float* __restrict__ outp) {
    __shared__ float red[256];
    __shared__ float tot[5];
    int t = threadIdx.x;
#pragma unroll
    for (int s = 0; s < 5; ++s) {
        float a = 0.f;
        for (int i = t; i < NBLK_E; i += 256) a += blksums[(size_t)s * NBLK_E + i];
        red[t] = a;
        __syncthreads();
        for (int st = 128; st > 0; st >>= 1) {
            if (t < st) red[t] += red[t + st];
            __syncthreads();
        }
        if (t == 0) tot[s] = red[0];
        __syncthreads();
    }
    if (t == 0) {
        float np_ = fmaxf(tot[0], 1.f), nn_ = fmaxf(tot[1], 1.f);
        outp[0] = 0.5f * (tot[2] / np_ + tot[3] / nn_);  // cls_loss
        outp[1] = tot[4] / (np_ * 4.f);                  // reg_loss
    }
}

extern "C" void kernel_launch(void* const* d_in, const int* in_sizes, int n_in,
                              void* d_out, int out_size, void* d_ws, size_t ws_size,
                              hipStream_t stream) {
    (void)in_sizes; (void)n_in; (void)out_size;
    const float* feat   = (const float*)d_in[0];
    const float* gtb    = (const float*)d_in[1];
    const int*   gtc    = (const int*)d_in[2];
    const float* conv_w = (const float*)d_in[3];
    const float* conv_b = (const float*)d_in[4];
    const float* cls_w  = (const float*)d_in[5];
    const float* cls_b  = (const float*)d_in[6];
    const float* box_w  = (const float*)d_in[7];
    const float* box_b  = (const float*)d_in[8];
    float* outp = (float*)d_out;
    float* ws   = (float*)d_ws;

    // workspace layout (floats)
    unsigned short* Bfrag   = (unsigned short*)ws;            // 110592 us = 55296 fl
    float*          effb    = ws + 55296;                     // 64
    float*          maxiou  = ws + 55360;                     // 128 (pad)
    float*          blksums = ws + 55552;                     // 5*2176 = 10880 -> pad 11264
    float*          convOut = ws + 66816;                     // 16*3844*48 = 2951168
    unsigned short* ft      = (unsigned short*)(ws + 3017984); // g * 1048576 ushorts

    // batch-group size: largest g in {16,8,4,2,1} that fits the workspace
    size_t avail = ws_size / 4;
    int g = 16;
    while (g > 1 && (size_t)3017984 + (size_t)g * 524288 > avail) g >>= 1;
    int g0 = g;

    prep_all<<<561 + 256 * g0, 256, 0, stream>>>(feat, conv_w, conv_b, cls_w, cls_b,
                                                 box_w, box_b, gtb, Bfrag, effb, maxiou, ft);
    conv_mfma<<<31 * g0, 256, 0, stream>>>(ft, Bfrag, effb, convOut, 0);
    for (int b0 = g0; b0 < NBAT; b0 += g) {
        to_bf16<<<dim3(32, 8, g), 256, 0, stream>>>(feat, ft, b0);
        conv_mfma<<<31 * g, 256, 0, stream>>>(ft, Bfrag, effb, convOut, b0);
    }
    epilogue_k<<<dim3(136, NBAT), 256, 0, stream>>>(convOut, gtb, gtc, maxiou,
                                                    outp, blksums);
    finalize<<<1, 256, 0, stream>>>(blksums, outp);
}